// Round 1
// baseline (1323.878 us; speedup 1.0000x reference)
//
#include <hip/hip_runtime.h>
#include <hip/hip_bf16.h>
#include <math.h>

// Problem dims
#define NRES 768
#define CS   384
#define CZ   128
#define CH   16
#define NH   12
#define PQK  4
#define PV   8
// derived
#define QCOLS   (NH*CH)        // 192
#define KVCOLS  (2*NH*CH)      // 384
#define QPCOLS  (NH*PQK*3)     // 144
#define KVPCOLS (NH*(PQK+PV)*3)// 432
#define CATC    (NH*(CZ+CH+PV*4)) // 2112

__global__ __launch_bounds__(256) void proj_kernel(
    const float* __restrict__ s,
    const float* __restrict__ Wq,  const float* __restrict__ bq,
    const float* __restrict__ Wkv, const float* __restrict__ bkv,
    const float* __restrict__ Wqp, const float* __restrict__ bqp,
    const float* __restrict__ Wkvp,const float* __restrict__ bkvp,
    float* __restrict__ proj_q, float* __restrict__ proj_kv,
    float* __restrict__ proj_qp, float* __restrict__ proj_kvp)
{
    const int R = 4;
    __shared__ float s_lds[4][CS];
    int n0 = blockIdx.x * R;
    int tid = threadIdx.x;
    for (int i = tid; i < R*CS; i += 256) s_lds[i/CS][i%CS] = s[(size_t)n0*CS + i];
    __syncthreads();
    for (int j = tid; j < 1152; j += 256) {
        const float* W; const float* b; int col, ncol; float* dst; int dld;
        if (j < 192)      { W=Wq;   b=bq;   col=j;     ncol=QCOLS;   dst=proj_q  + (size_t)n0*QCOLS  +col; dld=QCOLS;   }
        else if (j < 576) { W=Wkv;  b=bkv;  col=j-192; ncol=KVCOLS;  dst=proj_kv + (size_t)n0*KVCOLS +col; dld=KVCOLS;  }
        else if (j < 720) { W=Wqp;  b=bqp;  col=j-576; ncol=QPCOLS;  dst=proj_qp + (size_t)n0*QPCOLS +col; dld=QPCOLS;  }
        else              { W=Wkvp; b=bkvp; col=j-720; ncol=KVPCOLS; dst=proj_kvp+ (size_t)n0*KVPCOLS+col; dld=KVPCOLS; }
        float acc[4] = {0.f,0.f,0.f,0.f};
        for (int c = 0; c < CS; ++c) {
            float w = W[(size_t)c*ncol + col];
            #pragma unroll
            for (int r = 0; r < 4; ++r) acc[r] += s_lds[r][c] * w;
        }
        float bias = b[col];
        #pragma unroll
        for (int r = 0; r < 4; ++r) dst[(size_t)r*dld] = acc[r] + bias;
    }
}

__global__ __launch_bounds__(256) void rotpts_kernel(
    const float* __restrict__ rot, const float* __restrict__ trans,
    const float* __restrict__ proj_qp, const float* __restrict__ proj_kvp,
    float* __restrict__ q_pts, float* __restrict__ k_pts, float* __restrict__ v_pts)
{
    int g = blockIdx.x*256 + threadIdx.x;
    const int NQ = NRES*48;   // 36864 q-points
    if (g < NQ) {
        int n = g/48, rem = g%48;
        float p0 = proj_qp[(size_t)n*QPCOLS + 0*48 + rem];
        float p1 = proj_qp[(size_t)n*QPCOLS + 1*48 + rem];
        float p2 = proj_qp[(size_t)n*QPCOLS + 2*48 + rem];
        const float* Rm = rot + (size_t)n*9; const float* t = trans + (size_t)n*3;
        #pragma unroll
        for (int i = 0; i < 3; ++i)
            q_pts[((size_t)n*48+rem)*3 + i] = Rm[i*3]*p0 + Rm[i*3+1]*p1 + Rm[i*3+2]*p2 + t[i];
    } else {
        int g2 = g - NQ;
        if (g2 >= NRES*144) return;
        int n = g2/144, rem = g2%144;
        int h = rem/12, p = rem%12;
        float p0 = proj_kvp[(size_t)n*KVPCOLS + 0*144 + rem];
        float p1 = proj_kvp[(size_t)n*KVPCOLS + 1*144 + rem];
        float p2 = proj_kvp[(size_t)n*KVPCOLS + 2*144 + rem];
        const float* Rm = rot + (size_t)n*9; const float* t = trans + (size_t)n*3;
        float o[3];
        #pragma unroll
        for (int i=0;i<3;++i) o[i] = Rm[i*3]*p0 + Rm[i*3+1]*p1 + Rm[i*3+2]*p2 + t[i];
        if (p < PQK) {
            size_t d = ((size_t)n*48 + h*4 + p)*3;
            k_pts[d]=o[0]; k_pts[d+1]=o[1]; k_pts[d+2]=o[2];
        } else {
            size_t d = ((size_t)n*96 + h*8 + (p-4))*3;
            v_pts[d]=o[0]; v_pts[d+1]=o[1]; v_pts[d+2]=o[2];
        }
    }
}

__global__ __launch_bounds__(256) void attn_kernel(
    const float* __restrict__ z, const float* __restrict__ rot, const float* __restrict__ trans,
    const float* __restrict__ mask, const float* __restrict__ head_w,
    const float* __restrict__ W_b, const float* __restrict__ b_b,
    const float* __restrict__ proj_q, const float* __restrict__ proj_kv,
    const float* __restrict__ q_pts, const float* __restrict__ k_pts, const float* __restrict__ v_pts,
    float* __restrict__ cat)
{
    const int q = blockIdx.x;
    const int tid = threadIdx.x;

    __shared__ float a_lds[NH][NRES];      // 36864 B
    __shared__ float zbuf[32][CZ];         // 16384 B
    __shared__ float Wb_lds[CZ*13];        // 6656 B (pad 12->13)
    __shared__ float qvec[QCOLS];          // 768 B
    __shared__ float qp_lds[144];          // 576 B
    __shared__ float coef[NH];
    __shared__ float bb_s[NH];
    __shared__ float tilde[480];           // o(192) + o_pt(288)

    if (tid < QCOLS) qvec[tid] = proj_q[(size_t)q*QCOLS + tid];
    if (tid < 144)   qp_lds[tid] = q_pts[(size_t)q*144 + tid];
    for (int i = tid; i < CZ*NH; i += 256) { int c = i/NH, h = i%NH; Wb_lds[c*13+h] = W_b[i]; }
    if (tid < NH) {
        bb_s[tid] = b_b[tid];
        float x = head_w[tid];
        float sp = (x > 20.f) ? x : log1pf(__expf(x));
        coef[tid] = -0.5f * sp * 0.13608276348795434f;   // sqrt(1/54)
    }
    const float mq = mask[q];
    __syncthreads();

    const float scale_qk = 0.14433756729740643f;  // sqrt(1/48)
    const float scale_b  = 0.5773502691896258f;   // sqrt(1/3)

    // ---- Phase A: logits (all 12 heads), thread-per-k, 3 passes ----
    for (int pass = 0; pass < 3; ++pass) {
        int k = pass*256 + tid;
        const float* krow = proj_kv + (size_t)k*KVCOLS;
        const float* kp   = k_pts   + (size_t)k*144;
        const float* zrow = z + ((size_t)q*NRES + k)*CZ;
        float mterm = 100000.0f * (mq * mask[k] - 1.0f);
        float lg[NH];
        #pragma unroll
        for (int h = 0; h < NH; ++h) {
            float d = 0.f;
            #pragma unroll
            for (int c = 0; c < CH; ++c) d += qvec[h*CH+c] * krow[h*32+c];
            lg[h] = d * scale_qk;
        }
        #pragma unroll
        for (int h = 0; h < NH; ++h) {
            float d2s = 0.f;
            #pragma unroll
            for (int r = 0; r < 12; ++r) { float t = qp_lds[h*12+r] - kp[h*12+r]; d2s += t*t; }
            lg[h] += coef[h]*d2s;
        }
        float bp[NH];
        #pragma unroll
        for (int h=0;h<NH;++h) bp[h] = bb_s[h];
        for (int cb = 0; cb < CZ; cb += 4) {
            float4 zv = *(const float4*)(zrow + cb);
            #pragma unroll
            for (int h=0; h<NH; ++h) {
                bp[h] += zv.x*Wb_lds[(cb+0)*13+h] + zv.y*Wb_lds[(cb+1)*13+h]
                       + zv.z*Wb_lds[(cb+2)*13+h] + zv.w*Wb_lds[(cb+3)*13+h];
            }
        }
        #pragma unroll
        for (int h=0;h<NH;++h) a_lds[h][k] = lg[h] + scale_b*bp[h] + mterm;
    }
    __syncthreads();

    // ---- Phase B: softmax over k, wave w handles heads 3w..3w+2 ----
    int wv = tid >> 6, ln = tid & 63;
    for (int hh = 0; hh < 3; ++hh) {
        int h = wv*3 + hh;
        float m = -1e30f;
        for (int i = ln; i < NRES; i += 64) m = fmaxf(m, a_lds[h][i]);
        #pragma unroll
        for (int o = 32; o > 0; o >>= 1) m = fmaxf(m, __shfl_xor(m, o, 64));
        float ssum = 0.f;
        for (int i = ln; i < NRES; i += 64) {
            float e = __expf(a_lds[h][i] - m);
            a_lds[h][i] = e;
            ssum += e;
        }
        #pragma unroll
        for (int o = 32; o > 0; o >>= 1) ssum += __shfl_xor(ssum, o, 64);
        float inv = 1.f/ssum;
        for (int i = ln; i < NRES; i += 64) a_lds[h][i] *= inv;
    }
    __syncthreads();

    // ---- Phase C: o (192) and o_pt tilde (288) ----
    for (int j = tid; j < 480; j += 256) {
        float acc = 0.f;
        if (j < 192) {
            int h = j >> 4;
            const float* src = proj_kv + h*32 + 16 + (j & 15);
            const float* arow = a_lds[h];
            for (int k = 0; k < NRES; ++k) acc += arow[k]*src[(size_t)k*KVCOLS];
        } else {
            int jj = j - 192;
            int h = jj/24;
            const float* src = v_pts + jj;
            const float* arow = a_lds[h];
            for (int k = 0; k < NRES; ++k) acc += arow[k]*src[(size_t)k*288];
        }
        tilde[j] = acc;
    }
    __syncthreads();

    // ---- Epilogue part 1: o, rotated points, norms ----
    float* crow = cat + (size_t)q*CATC;
    if (tid < 192) crow[tid] = tilde[tid];
    if (tid < 96) {
        int h = tid >> 3, p = tid & 7;
        float b0 = tilde[192 + h*24 + p*3 + 0] - trans[q*3+0];
        float b1 = tilde[192 + h*24 + p*3 + 1] - trans[q*3+1];
        float b2 = tilde[192 + h*24 + p*3 + 2] - trans[q*3+2];
        const float* Rm = rot + (size_t)q*9;
        float v0 = Rm[0]*b0 + Rm[3]*b1 + Rm[6]*b2;
        float v1 = Rm[1]*b0 + Rm[4]*b1 + Rm[7]*b2;
        float v2 = Rm[2]*b0 + Rm[5]*b1 + Rm[8]*b2;
        crow[192 + tid] = v0;
        crow[288 + tid] = v1;
        crow[384 + tid] = v2;
        crow[480 + tid] = sqrtf(v0*v0 + v1*v1 + v2*v2 + 1e-8f);
    }

    // ---- Phase D: o_pair (12*128 outputs), z staged in LDS, float2 per thread ----
    float2 acc2[3];
    int h2[3], c2[3];
    #pragma unroll
    for (int i = 0; i < 3; ++i) {
        int j = i*256 + tid;        // pair index 0..767
        h2[i] = j >> 6;             // 64 pairs per head
        c2[i] = (j & 63)*2;
        acc2[i].x = 0.f; acc2[i].y = 0.f;
    }
    for (int kc = 0; kc < NRES; kc += 32) {
        const float4* zsrc = (const float4*)(z + ((size_t)q*NRES + kc)*CZ);
        float4* zd = (float4*)&zbuf[0][0];
        for (int i = tid; i < 1024; i += 256) zd[i] = zsrc[i];
        __syncthreads();
        #pragma unroll
        for (int i = 0; i < 3; ++i) {
            const float* arow = &a_lds[h2[i]][kc];
            float2 a2 = acc2[i];
            int c = c2[i];
            for (int kk = 0; kk < 32; ++kk) {
                float aw = arow[kk];
                a2.x += aw * zbuf[kk][c];
                a2.y += aw * zbuf[kk][c+1];
            }
            acc2[i] = a2;
        }
        __syncthreads();
    }
    #pragma unroll
    for (int i = 0; i < 3; ++i) {
        int j = i*256 + tid;
        crow[576 + 2*j]     = acc2[i].x;
        crow[576 + 2*j + 1] = acc2[i].y;
    }
}

__global__ __launch_bounds__(256) void outgemm_kernel(
    const float* __restrict__ cat, const float* __restrict__ W_out,
    const float* __restrict__ b_out, float* __restrict__ out)
{
    __shared__ float Al[16][32];
    __shared__ float Bl[32][128];
    int q0 = blockIdx.x * 16;
    int j0 = blockIdx.y * 128;
    int tid = threadIdx.x;
    int jc = tid & 127;
    int rb = (tid >> 7) * 8;
    float acc[8] = {0,0,0,0,0,0,0,0};
    for (int kc = 0; kc < CATC; kc += 32) {
        #pragma unroll
        for (int ii = 0; ii < 2; ++ii) {
            int i = tid + ii*256;
            Al[i>>5][i&31] = cat[(size_t)(q0 + (i>>5))*CATC + kc + (i&31)];
        }
        #pragma unroll
        for (int ii = 0; ii < 16; ++ii) {
            int i = tid + ii*256;
            Bl[i>>7][i&127] = W_out[(size_t)(kc + (i>>7))*384 + j0 + (i&127)];
        }
        __syncthreads();
        #pragma unroll
        for (int kk = 0; kk < 32; ++kk) {
            float bv = Bl[kk][jc];
            #pragma unroll
            for (int r = 0; r < 8; ++r) acc[r] += Al[rb + r][kk]*bv;
        }
        __syncthreads();
    }
    float bias = b_out[j0 + jc];
    #pragma unroll
    for (int r = 0; r < 8; ++r) out[(size_t)(q0 + rb + r)*384 + j0 + jc] = acc[r] + bias;
}

extern "C" void kernel_launch(void* const* d_in, const int* in_sizes, int n_in,
                              void* d_out, int out_size, void* d_ws, size_t ws_size,
                              hipStream_t stream) {
    const float* s      = (const float*)d_in[0];
    const float* z      = (const float*)d_in[1];
    const float* rot    = (const float*)d_in[2];
    const float* trans  = (const float*)d_in[3];
    const float* mask   = (const float*)d_in[4];
    const float* W_q    = (const float*)d_in[5];
    const float* b_q    = (const float*)d_in[6];
    const float* W_kv   = (const float*)d_in[7];
    const float* b_kv   = (const float*)d_in[8];
    const float* W_qp   = (const float*)d_in[9];
    const float* b_qp   = (const float*)d_in[10];
    const float* W_kvp  = (const float*)d_in[11];
    const float* b_kvp  = (const float*)d_in[12];
    const float* W_b    = (const float*)d_in[13];
    const float* b_b    = (const float*)d_in[14];
    const float* head_w = (const float*)d_in[15];
    const float* W_out  = (const float*)d_in[16];
    const float* b_out  = (const float*)d_in[17];

    float* ws = (float*)d_ws;
    float* proj_q   = ws;                 // 768*192  = 147456
    float* proj_kv  = ws + 147456;        // 768*384  = 294912
    float* proj_qp  = ws + 442368;        // 768*144  = 110592
    float* proj_kvp = ws + 552960;        // 768*432  = 331776
    float* q_pts    = ws + 884736;        // 768*144  = 110592
    float* k_pts    = ws + 995328;        // 768*144  = 110592
    float* v_pts    = ws + 1105920;       // 768*288  = 221184
    float* cat      = ws + 1327104;       // 768*2112 = 1622016
    float* out = (float*)d_out;

    proj_kernel<<<NRES/4, 256, 0, stream>>>(s, W_q, b_q, W_kv, b_kv, W_qp, b_qp, W_kvp, b_kvp,
                                            proj_q, proj_kv, proj_qp, proj_kvp);
    rotpts_kernel<<<(NRES*48 + NRES*144)/256, 256, 0, stream>>>(rot, trans, proj_qp, proj_kvp,
                                                                q_pts, k_pts, v_pts);
    attn_kernel<<<NRES, 256, 0, stream>>>(z, rot, trans, mask, head_w, W_b, b_b,
                                          proj_q, proj_kv, q_pts, k_pts, v_pts, cat);
    outgemm_kernel<<<dim3(NRES/16, 384/128), 256, 0, stream>>>(cat, W_out, b_out, out);
}

// Round 2
// 949.421 us; speedup vs baseline: 1.3944x; 1.3944x over previous
//
#include <hip/hip_runtime.h>
#include <hip/hip_bf16.h>
#include <math.h>

// Problem dims
#define NRES 768
#define CS   384
#define CZ   128
#define CH   16
#define NH   12
#define PQK  4
#define PV   8
#define QCOLS   (NH*CH)        // 192
#define KVCOLS  (2*NH*CH)      // 384
#define QPCOLS  (NH*PQK*3)     // 144
#define KVPCOLS (NH*(PQK+PV)*3)// 432
#define CATC    (NH*(CZ+CH+PV*4)) // 2112
#define NN      (NRES*NRES)    // 589824

__global__ __launch_bounds__(256) void proj_kernel(
    const float* __restrict__ s,
    const float* __restrict__ Wq,  const float* __restrict__ bq,
    const float* __restrict__ Wkv, const float* __restrict__ bkv,
    const float* __restrict__ Wqp, const float* __restrict__ bqp,
    const float* __restrict__ Wkvp,const float* __restrict__ bkvp,
    float* __restrict__ proj_q, float* __restrict__ proj_kv,
    float* __restrict__ proj_qp, float* __restrict__ proj_kvp)
{
    const int R = 4;
    __shared__ float s_lds[4][CS];
    int n0 = blockIdx.x * R;
    int tid = threadIdx.x;
    for (int i = tid; i < R*CS; i += 256) s_lds[i/CS][i%CS] = s[(size_t)n0*CS + i];
    __syncthreads();
    for (int j = tid; j < 1152; j += 256) {
        const float* W; const float* b; int col, ncol; float* dst; int dld;
        if (j < 192)      { W=Wq;   b=bq;   col=j;     ncol=QCOLS;   dst=proj_q  + (size_t)n0*QCOLS  +col; dld=QCOLS;   }
        else if (j < 576) { W=Wkv;  b=bkv;  col=j-192; ncol=KVCOLS;  dst=proj_kv + (size_t)n0*KVCOLS +col; dld=KVCOLS;  }
        else if (j < 720) { W=Wqp;  b=bqp;  col=j-576; ncol=QPCOLS;  dst=proj_qp + (size_t)n0*QPCOLS +col; dld=QPCOLS;  }
        else              { W=Wkvp; b=bkvp; col=j-720; ncol=KVPCOLS; dst=proj_kvp+ (size_t)n0*KVPCOLS+col; dld=KVPCOLS; }
        float acc[4] = {0.f,0.f,0.f,0.f};
        for (int c = 0; c < CS; ++c) {
            float w = W[(size_t)c*ncol + col];
            #pragma unroll
            for (int r = 0; r < 4; ++r) acc[r] += s_lds[r][c] * w;
        }
        float bias = b[col];
        #pragma unroll
        for (int r = 0; r < 4; ++r) dst[(size_t)r*dld] = acc[r] + bias;
    }
}

// points + build VcatT[480][768] (v cols + v_pts cols per head: h*40 = [16 v | 24 pts])
__global__ __launch_bounds__(256) void rotpts_kernel(
    const float* __restrict__ rot, const float* __restrict__ trans,
    const float* __restrict__ proj_kv,
    const float* __restrict__ proj_qp, const float* __restrict__ proj_kvp,
    float* __restrict__ q_pts, float* __restrict__ k_pts, float* __restrict__ vcatT)
{
    int g = blockIdx.x*256 + threadIdx.x;
    const int NQ = NRES*48;          // 36864
    const int NKV = NRES*144;        // 110592
    if (g < NQ) {
        int n = g/48, rem = g%48;
        float p0 = proj_qp[(size_t)n*QPCOLS + 0*48 + rem];
        float p1 = proj_qp[(size_t)n*QPCOLS + 1*48 + rem];
        float p2 = proj_qp[(size_t)n*QPCOLS + 2*48 + rem];
        const float* Rm = rot + (size_t)n*9; const float* t = trans + (size_t)n*3;
        #pragma unroll
        for (int i = 0; i < 3; ++i)
            q_pts[((size_t)n*48+rem)*3 + i] = Rm[i*3]*p0 + Rm[i*3+1]*p1 + Rm[i*3+2]*p2 + t[i];
    } else if (g < NQ + NKV) {
        int g2 = g - NQ;
        int n = g2/144, rem = g2%144;
        int h = rem/12, p = rem%12;
        float p0 = proj_kvp[(size_t)n*KVPCOLS + 0*144 + rem];
        float p1 = proj_kvp[(size_t)n*KVPCOLS + 1*144 + rem];
        float p2 = proj_kvp[(size_t)n*KVPCOLS + 2*144 + rem];
        const float* Rm = rot + (size_t)n*9; const float* t = trans + (size_t)n*3;
        float o[3];
        #pragma unroll
        for (int i=0;i<3;++i) o[i] = Rm[i*3]*p0 + Rm[i*3+1]*p1 + Rm[i*3+2]*p2 + t[i];
        if (p < PQK) {
            size_t d = ((size_t)n*48 + h*4 + p)*3;
            k_pts[d]=o[0]; k_pts[d+1]=o[1]; k_pts[d+2]=o[2];
        } else {
            #pragma unroll
            for (int i=0;i<3;++i)
                vcatT[(size_t)(h*40 + 16 + (p-4)*3 + i)*NRES + n] = o[i];
        }
    } else {
        int g3 = g - NQ - NKV;       // 0 .. 147455  (v copy)
        if (g3 >= NRES*192) return;
        int col = g3/768, k = g3%768;
        int h = col>>4, c = col&15;
        vcatT[(size_t)(h*40 + c)*NRES + k] = proj_kv[(size_t)k*KVCOLS + h*32 + 16 + c];
    }
}

// logits: 16x16 (q,k) tile per block, all 12 heads -> lg[h][q][k]
__global__ __launch_bounds__(256) void logits_kernel(
    const float* __restrict__ z, const float* __restrict__ mask,
    const float* __restrict__ head_w, const float* __restrict__ W_b, const float* __restrict__ b_b,
    const float* __restrict__ proj_q, const float* __restrict__ proj_kv,
    const float* __restrict__ q_pts, const float* __restrict__ k_pts,
    float* __restrict__ lg)
{
    __shared__ float zt[256*17];       // 17408 B
    __shared__ float qbuf[16*196];     // 12544 B
    __shared__ float kbuf[16*196];     // 12544 B
    __shared__ float qpbuf[16*148];    // 9472 B
    __shared__ float kpbuf[16*148];    // 9472 B

    const int tid = threadIdx.x;
    const int k0 = blockIdx.x * 16;
    const int q0 = blockIdx.y * 16;
    const int qi = tid >> 4, ki = tid & 15;

    for (int i = tid; i < 16*192; i += 256) {
        int r = i / 192, c = i % 192;
        qbuf[r*196 + c] = proj_q[(size_t)(q0+r)*QCOLS + c];
        int h = c >> 4, cc = c & 15;
        kbuf[r*196 + c] = proj_kv[(size_t)(k0+r)*KVCOLS + h*32 + cc];
    }
    for (int i = tid; i < 16*144; i += 256) {
        int r = i / 144, c = i % 144;
        qpbuf[r*148 + c] = q_pts[(size_t)(q0+r)*144 + c];
        kpbuf[r*148 + c] = k_pts[(size_t)(k0+r)*144 + c];
    }

    float bp[12];
    #pragma unroll
    for (int h = 0; h < 12; ++h) bp[h] = 0.f;

    for (int cc = 0; cc < 8; ++cc) {
        __syncthreads();
        #pragma unroll
        for (int j = 0; j < 4; ++j) {
            int i = tid + 256*j;           // 0..1023
            int row = i >> 2, c4 = i & 3;  // row = qi*16+ki
            int qq = row >> 4, kk = row & 15;
            const float4 v = *(const float4*)(z + ((size_t)(q0+qq)*NRES + (k0+kk))*CZ + cc*16 + c4*4);
            float* d = &zt[row*17 + c4*4];
            d[0]=v.x; d[1]=v.y; d[2]=v.z; d[3]=v.w;
        }
        __syncthreads();
        const float* zrow = &zt[tid*17];
        #pragma unroll
        for (int c = 0; c < 16; ++c) {
            float zv = zrow[c];
            const float* wb = &W_b[(cc*16+c)*NH];   // wave-uniform -> scalar loads
            #pragma unroll
            for (int h = 0; h < 12; ++h) bp[h] += zv * wb[h];
        }
    }

    const float scale_qk = 0.14433756729740643f;  // sqrt(1/48)
    const float scale_b  = 0.5773502691896258f;   // sqrt(1/3)
    float mterm = 100000.0f * (mask[q0+qi]*mask[k0+ki] - 1.0f);
    const float4* qv = (const float4*)&qbuf[qi*196];
    const float4* kv = (const float4*)&kbuf[ki*196];
    const float4* qp = (const float4*)&qpbuf[qi*148];
    const float4* kp = (const float4*)&kpbuf[ki*148];
    size_t outbase = (size_t)(q0+qi)*NRES + (k0+ki);
    #pragma unroll
    for (int h = 0; h < 12; ++h) {
        float d = 0.f;
        #pragma unroll
        for (int j = 0; j < 4; ++j) {
            float4 a = qv[h*4+j], b = kv[h*4+j];
            d += a.x*b.x + a.y*b.y + a.z*b.z + a.w*b.w;
        }
        float d2 = 0.f;
        #pragma unroll
        for (int j = 0; j < 3; ++j) {
            float4 a = qp[h*3+j], b = kp[h*3+j];
            float t0=a.x-b.x, t1=a.y-b.y, t2=a.z-b.z, t3=a.w-b.w;
            d2 += t0*t0+t1*t1+t2*t2+t3*t3;
        }
        float x = head_w[h];
        float sp = (x > 20.f) ? x : log1pf(__expf(x));
        float coef = -0.5f * sp * 0.13608276348795434f;   // sqrt(1/54)
        lg[(size_t)h*NN + outbase] = d*scale_qk + scale_b*(bp[h] + b_b[h]) + coef*d2 + mterm;
    }
}

// softmax (in-place on lg) + o + o_pt(tilde) ; wave per (h,q) row
__global__ __launch_bounds__(256) void softmax_opt_kernel(
    float* __restrict__ lg, const float* __restrict__ vcatT,
    float* __restrict__ cat, float* __restrict__ optt)
{
    int row = blockIdx.x*4 + (threadIdx.x >> 6);
    int ln = threadIdx.x & 63;
    int h = row / NRES, q = row % NRES;
    float* arow = lg + (size_t)h*NN + (size_t)q*NRES;
    float4 a[3];
    #pragma unroll
    for (int i=0;i<3;++i) a[i] = *(const float4*)(arow + ln*4 + i*256);
    float m = -1e30f;
    #pragma unroll
    for (int i=0;i<3;++i) m = fmaxf(m, fmaxf(fmaxf(a[i].x,a[i].y),fmaxf(a[i].z,a[i].w)));
    #pragma unroll
    for (int o=32;o>0;o>>=1) m = fmaxf(m, __shfl_xor(m,o,64));
    float s = 0.f;
    #pragma unroll
    for (int i=0;i<3;++i) {
        a[i].x = __expf(a[i].x-m); a[i].y = __expf(a[i].y-m);
        a[i].z = __expf(a[i].z-m); a[i].w = __expf(a[i].w-m);
        s += a[i].x + a[i].y + a[i].z + a[i].w;
    }
    #pragma unroll
    for (int o=32;o>0;o>>=1) s += __shfl_xor(s,o,64);
    float inv = 1.f/s;
    #pragma unroll
    for (int i=0;i<3;++i) {
        a[i].x*=inv; a[i].y*=inv; a[i].z*=inv; a[i].w*=inv;
        *(float4*)(arow + ln*4 + i*256) = a[i];
    }
    // o (16 cols) + o_pt tilde (24 cols), coalesced VcatT rows
    for (int col = 0; col < 40; ++col) {
        const float* vrow = vcatT + (size_t)(h*40+col)*NRES;
        float p = 0.f;
        #pragma unroll
        for (int i=0;i<3;++i) {
            float4 v = *(const float4*)(vrow + ln*4 + i*256);
            p += a[i].x*v.x + a[i].y*v.y + a[i].z*v.z + a[i].w*v.w;
        }
        #pragma unroll
        for (int o=32;o>0;o>>=1) p += __shfl_xor(p,o,64);
        if (ln == 0) {
            if (col < 16) cat[(size_t)q*CATC + h*16 + col] = p;
            else          optt[(size_t)q*288 + h*24 + (col-16)] = p;
        }
    }
}

// o_pair: block per q; k-split accumulators, z staged coalesced in LDS (read once)
__global__ __launch_bounds__(256) void opair_kernel(
    const float* __restrict__ z, const float* __restrict__ lg,
    const float* __restrict__ rot, const float* __restrict__ trans,
    const float* __restrict__ optt, float* __restrict__ cat)
{
    __shared__ float smem[13440];      // abuf[9216] | zbuf[32*132]
    float* abuf = smem;
    float* zbuf = smem + 9216;
    const int q = blockIdx.x, tid = threadIdx.x;
    float* crow = cat + (size_t)q*CATC;

    for (int i = tid; i < 2304; i += 256) {
        int h = i / 192, kk4 = i % 192;
        ((float4*)abuf)[h*192 + kk4] =
            *(const float4*)(lg + (size_t)h*NN + (size_t)q*NRES + kk4*4);
    }
    // epilogue: rotate o_pt tilde, norms (independent of z loop)
    if (tid < 96) {
        int h = tid>>3, p = tid&7;
        float b0 = optt[(size_t)q*288 + h*24+p*3+0] - trans[q*3+0];
        float b1 = optt[(size_t)q*288 + h*24+p*3+1] - trans[q*3+1];
        float b2 = optt[(size_t)q*288 + h*24+p*3+2] - trans[q*3+2];
        const float* Rm = rot + (size_t)q*9;
        float v0 = Rm[0]*b0 + Rm[3]*b1 + Rm[6]*b2;
        float v1 = Rm[1]*b0 + Rm[4]*b1 + Rm[7]*b2;
        float v2 = Rm[2]*b0 + Rm[5]*b1 + Rm[8]*b2;
        crow[192 + tid] = v0;
        crow[288 + tid] = v1;
        crow[384 + tid] = v2;
        crow[480 + tid] = sqrtf(v0*v0 + v1*v1 + v2*v2 + 1e-8f);
    }

    const int ks = tid>>5, c4 = tid&31;
    float4 acc[12];
    #pragma unroll
    for (int h=0;h<12;++h) { acc[h].x=0; acc[h].y=0; acc[h].z=0; acc[h].w=0; }

    for (int kc = 0; kc < NRES; kc += 32) {
        __syncthreads();
        #pragma unroll
        for (int j = 0; j < 4; ++j) {
            int i = tid + 256*j;
            int r = i>>5, cc = i&31;
            float4 v = *(const float4*)(z + ((size_t)q*NRES + kc + r)*CZ + cc*4);
            *(float4*)&zbuf[r*132 + cc*4] = v;
        }
        __syncthreads();
        float4 av[12];
        #pragma unroll
        for (int h=0;h<12;++h)
            av[h] = *(const float4*)(abuf + h*768 + kc + ks*4);
        #pragma unroll
        for (int i=0;i<4;++i) {
            float4 zv = *(const float4*)(&zbuf[(ks*4+i)*132 + c4*4]);
            #pragma unroll
            for (int h=0;h<12;++h) {
                float aw = (i==0)?av[h].x:(i==1)?av[h].y:(i==2)?av[h].z:av[h].w;
                acc[h].x += aw*zv.x; acc[h].y += aw*zv.y;
                acc[h].z += aw*zv.z; acc[h].w += aw*zv.w;
            }
        }
    }
    __syncthreads();
    #pragma unroll
    for (int h=0;h<12;++h) *((float4*)&smem[tid*48 + h*4]) = acc[h];
    __syncthreads();
    for (int o = tid; o < 384; o += 256) {
        int h = o >> 5, cc = o & 31;
        float4 r = {0,0,0,0};
        #pragma unroll
        for (int k2=0;k2<8;++k2) {
            float4 p = *(const float4*)&smem[(k2*32+cc)*48 + h*4];
            r.x+=p.x; r.y+=p.y; r.z+=p.z; r.w+=p.w;
        }
        *(float4*)(crow + 576 + h*128 + cc*4) = r;
    }
}

__global__ __launch_bounds__(256) void outgemm_kernel(
    const float* __restrict__ cat, const float* __restrict__ W_out,
    const float* __restrict__ b_out, float* __restrict__ out)
{
    __shared__ float Al[16][32];
    __shared__ float Bl[32][128];
    int q0 = blockIdx.x * 16;
    int j0 = blockIdx.y * 128;
    int tid = threadIdx.x;
    int jc = tid & 127;
    int rb = (tid >> 7) * 8;
    float acc[8] = {0,0,0,0,0,0,0,0};
    for (int kc = 0; kc < CATC; kc += 32) {
        #pragma unroll
        for (int ii = 0; ii < 2; ++ii) {
            int i = tid + ii*256;
            Al[i>>5][i&31] = cat[(size_t)(q0 + (i>>5))*CATC + kc + (i&31)];
        }
        #pragma unroll
        for (int ii = 0; ii < 16; ++ii) {
            int i = tid + ii*256;
            Bl[i>>7][i&127] = W_out[(size_t)(kc + (i>>7))*384 + j0 + (i&127)];
        }
        __syncthreads();
        #pragma unroll
        for (int kk = 0; kk < 32; ++kk) {
            float bv = Bl[kk][jc];
            #pragma unroll
            for (int r = 0; r < 8; ++r) acc[r] += Al[rb + r][kk]*bv;
        }
        __syncthreads();
    }
    float bias = b_out[j0 + jc];
    #pragma unroll
    for (int r = 0; r < 8; ++r) out[(size_t)(q0 + rb + r)*384 + j0 + jc] = acc[r] + bias;
}

extern "C" void kernel_launch(void* const* d_in, const int* in_sizes, int n_in,
                              void* d_out, int out_size, void* d_ws, size_t ws_size,
                              hipStream_t stream) {
    const float* s      = (const float*)d_in[0];
    const float* z      = (const float*)d_in[1];
    const float* rot    = (const float*)d_in[2];
    const float* trans  = (const float*)d_in[3];
    const float* mask   = (const float*)d_in[4];
    const float* W_q    = (const float*)d_in[5];
    const float* b_q    = (const float*)d_in[6];
    const float* W_kv   = (const float*)d_in[7];
    const float* b_kv   = (const float*)d_in[8];
    const float* W_qp   = (const float*)d_in[9];
    const float* b_qp   = (const float*)d_in[10];
    const float* W_kvp  = (const float*)d_in[11];
    const float* b_kvp  = (const float*)d_in[12];
    const float* W_b    = (const float*)d_in[13];
    const float* b_b    = (const float*)d_in[14];
    const float* head_w = (const float*)d_in[15];
    const float* W_out  = (const float*)d_in[16];
    const float* b_out  = (const float*)d_in[17];

    float* ws = (float*)d_ws;
    float* proj_q   = ws;                 // 147456
    float* proj_kv  = ws + 147456;        // 294912
    float* proj_qp  = ws + 442368;        // 110592
    float* proj_kvp = ws + 552960;        // 331776
    float* q_pts    = ws + 884736;        // 110592
    float* k_pts    = ws + 995328;        // 110592
    float* vcatT    = ws + 1105920;       // 368640
    float* optt     = ws + 1474560;       // 221184
    float* cat      = ws + 1695744;       // 1622016
    float* lg       = ws + 3317760;       // 7077888  (end 10395648 floats = 41.6 MB)
    float* out = (float*)d_out;

    proj_kernel<<<NRES/4, 256, 0, stream>>>(s, W_q, b_q, W_kv, b_kv, W_qp, b_qp, W_kvp, b_kvp,
                                            proj_q, proj_kv, proj_qp, proj_kvp);
    rotpts_kernel<<<(NRES*48 + NRES*144 + NRES*192)/256, 256, 0, stream>>>(
        rot, trans, proj_kv, proj_qp, proj_kvp, q_pts, k_pts, vcatT);
    logits_kernel<<<dim3(48,48), 256, 0, stream>>>(z, mask, head_w, W_b, b_b,
                                                   proj_q, proj_kv, q_pts, k_pts, lg);
    softmax_opt_kernel<<<NRES*NH/4, 256, 0, stream>>>(lg, vcatT, cat, optt);
    opair_kernel<<<NRES, 256, 0, stream>>>(z, lg, rot, trans, optt, cat);
    outgemm_kernel<<<dim3(NRES/16, 384/128), 256, 0, stream>>>(cat, W_out, b_out, out);
}

// Round 3
// 944.867 us; speedup vs baseline: 1.4011x; 1.0048x over previous
//
#include <hip/hip_runtime.h>
#include <hip/hip_bf16.h>
#include <math.h>

// Problem dims
#define NRES 768
#define CS   384
#define CZ   128
#define CH   16
#define NH   12
#define PQK  4
#define PV   8
#define QCOLS   (NH*CH)        // 192
#define KVCOLS  (2*NH*CH)      // 384
#define QPCOLS  (NH*PQK*3)     // 144
#define KVPCOLS (NH*(PQK+PV)*3)// 432
#define CATC    (NH*(CZ+CH+PV*4)) // 2112
#define NN      (NRES*NRES)    // 589824

// proj: tiled GEMM s(768x384) @ {Wq|Wkv|Wqp|Wkvp}. Block = 64 rows x 48 cols.
// col tile of 48 divides all matrix boundaries (192, 576, 720).
__global__ __launch_bounds__(256) void proj_kernel(
    const float* __restrict__ s,
    const float* __restrict__ Wq,  const float* __restrict__ bq,
    const float* __restrict__ Wkv, const float* __restrict__ bkv,
    const float* __restrict__ Wqp, const float* __restrict__ bqp,
    const float* __restrict__ Wkvp,const float* __restrict__ bkvp,
    float* __restrict__ proj_q, float* __restrict__ proj_kv,
    float* __restrict__ proj_qp, float* __restrict__ proj_kvp)
{
    __shared__ float Al[32][68];   // [k][m]
    __shared__ float Bl[32][52];   // [k][n]
    const int mt = blockIdx.x;     // 0..11
    const int gc0 = blockIdx.y * 48;
    const float* W; const float* bb; int ncol; float* dst; int c0;
    if (gc0 < 192)      { W=Wq;   bb=bq;   ncol=QCOLS;   dst=proj_q;   c0=gc0; }
    else if (gc0 < 576) { W=Wkv;  bb=bkv;  ncol=KVCOLS;  dst=proj_kv;  c0=gc0-192; }
    else if (gc0 < 720) { W=Wqp;  bb=bqp;  ncol=QPCOLS;  dst=proj_qp;  c0=gc0-576; }
    else                { W=Wkvp; bb=bkvp; ncol=KVPCOLS; dst=proj_kvp; c0=gc0-720; }
    const int tid = threadIdx.x;
    const int m0 = (tid & 15)*4;
    const int n0 = (tid >> 4)*3;
    float acc[4][3] = {};
    for (int kc = 0; kc < CS; kc += 32) {
        #pragma unroll
        for (int f = tid; f < 512; f += 256) {
            int r = f >> 3, c4 = (f & 7)*4;
            float4 v = *(const float4*)(s + (size_t)(mt*64+r)*CS + kc + c4);
            Al[c4][r]=v.x; Al[c4+1][r]=v.y; Al[c4+2][r]=v.z; Al[c4+3][r]=v.w;
        }
        for (int f = tid; f < 384; f += 256) {
            int r = f / 12, c4 = (f % 12)*4;
            *(float4*)&Bl[r][c4] = *(const float4*)(W + (size_t)(kc+r)*ncol + c0 + c4);
        }
        __syncthreads();
        #pragma unroll
        for (int kk = 0; kk < 32; ++kk) {
            float4 a = *(const float4*)&Al[kk][m0];
            float b0 = Bl[kk][n0], b1 = Bl[kk][n0+1], b2 = Bl[kk][n0+2];
            acc[0][0]+=a.x*b0; acc[0][1]+=a.x*b1; acc[0][2]+=a.x*b2;
            acc[1][0]+=a.y*b0; acc[1][1]+=a.y*b1; acc[1][2]+=a.y*b2;
            acc[2][0]+=a.z*b0; acc[2][1]+=a.z*b1; acc[2][2]+=a.z*b2;
            acc[3][0]+=a.w*b0; acc[3][1]+=a.w*b1; acc[3][2]+=a.w*b2;
        }
        __syncthreads();
    }
    #pragma unroll
    for (int r = 0; r < 4; ++r)
        #pragma unroll
        for (int c = 0; c < 3; ++c)
            dst[(size_t)(mt*64+m0+r)*ncol + c0+n0+c] = acc[r][c] + bb[c0+n0+c];
}

// points + VcatT[480][768] + out bias init
__global__ __launch_bounds__(256) void rotpts_kernel(
    const float* __restrict__ rot, const float* __restrict__ trans,
    const float* __restrict__ proj_kv,
    const float* __restrict__ proj_qp, const float* __restrict__ proj_kvp,
    const float* __restrict__ b_out,
    float* __restrict__ q_pts, float* __restrict__ k_pts, float* __restrict__ vcatT,
    float* __restrict__ out)
{
    int g = blockIdx.x*256 + threadIdx.x;
    const int NQ = NRES*48;          // 36864
    const int NKV = NRES*144;        // 110592
    const int NV = NRES*192;         // 147456
    if (g < NQ) {
        int n = g/48, rem = g%48;
        float p0 = proj_qp[(size_t)n*QPCOLS + 0*48 + rem];
        float p1 = proj_qp[(size_t)n*QPCOLS + 1*48 + rem];
        float p2 = proj_qp[(size_t)n*QPCOLS + 2*48 + rem];
        const float* Rm = rot + (size_t)n*9; const float* t = trans + (size_t)n*3;
        #pragma unroll
        for (int i = 0; i < 3; ++i)
            q_pts[((size_t)n*48+rem)*3 + i] = Rm[i*3]*p0 + Rm[i*3+1]*p1 + Rm[i*3+2]*p2 + t[i];
    } else if (g < NQ + NKV) {
        int g2 = g - NQ;
        int n = g2/144, rem = g2%144;
        int h = rem/12, p = rem%12;
        float p0 = proj_kvp[(size_t)n*KVPCOLS + 0*144 + rem];
        float p1 = proj_kvp[(size_t)n*KVPCOLS + 1*144 + rem];
        float p2 = proj_kvp[(size_t)n*KVPCOLS + 2*144 + rem];
        const float* Rm = rot + (size_t)n*9; const float* t = trans + (size_t)n*3;
        float o[3];
        #pragma unroll
        for (int i=0;i<3;++i) o[i] = Rm[i*3]*p0 + Rm[i*3+1]*p1 + Rm[i*3+2]*p2 + t[i];
        if (p < PQK) {
            size_t d = ((size_t)n*48 + h*4 + p)*3;
            k_pts[d]=o[0]; k_pts[d+1]=o[1]; k_pts[d+2]=o[2];
        } else {
            #pragma unroll
            for (int i=0;i<3;++i)
                vcatT[(size_t)(h*40 + 16 + (p-4)*3 + i)*NRES + n] = o[i];
        }
    } else if (g < NQ + NKV + NV) {
        int g3 = g - NQ - NKV;
        int col = g3/768, k = g3%768;
        int h = col>>4, c = col&15;
        vcatT[(size_t)(h*40 + c)*NRES + k] = proj_kv[(size_t)k*KVCOLS + h*32 + 16 + c];
    } else {
        int g4 = g - NQ - NKV - NV;    // 0..294911: out = bias (outgemm atomically adds)
        if (g4 < NRES*CS) out[g4] = b_out[g4 % CS];
    }
}

// logits: 16x16 (q,k) tile per block -> lg[h][q][k]. Two LDS phases share one region.
__global__ __launch_bounds__(256) void logits_kernel(
    const float* __restrict__ z, const float* __restrict__ mask,
    const float* __restrict__ head_w, const float* __restrict__ W_b, const float* __restrict__ b_b,
    const float* __restrict__ proj_q, const float* __restrict__ proj_kv,
    const float* __restrict__ q_pts, const float* __restrict__ k_pts,
    float* __restrict__ lg)
{
    __shared__ float smem[11008];   // 44032 B: phase1 q/k/qp/kp, phase2 zt[256*37]
    float* qbuf  = smem;            // 16*196
    float* kbuf  = smem + 3136;     // 16*196
    float* qpbuf = smem + 6272;     // 16*148
    float* kpbuf = smem + 8640;     // 16*148

    const int tid = threadIdx.x;
    const int k0 = blockIdx.x * 16;
    const int q0 = blockIdx.y * 16;
    const int qi = tid >> 4, ki = tid & 15;

    for (int i = tid; i < 16*192; i += 256) {
        int r = i / 192, c = i % 192;
        qbuf[r*196 + c] = proj_q[(size_t)(q0+r)*QCOLS + c];
        int h = c >> 4, cc = c & 15;
        kbuf[r*196 + c] = proj_kv[(size_t)(k0+r)*KVCOLS + h*32 + cc];
    }
    for (int i = tid; i < 16*144; i += 256) {
        int r = i / 144, c = i % 144;
        qpbuf[r*148 + c] = q_pts[(size_t)(q0+r)*144 + c];
        kpbuf[r*148 + c] = k_pts[(size_t)(k0+r)*144 + c];
    }
    __syncthreads();

    const float scale_qk = 0.14433756729740643f;  // sqrt(1/48)
    const float scale_b  = 0.5773502691896258f;   // sqrt(1/3)
    const float mterm = 100000.0f * (mask[q0+qi]*mask[k0+ki] - 1.0f);
    float lgp[12];
    {
        const float4* qv = (const float4*)&qbuf[qi*196];
        const float4* kv = (const float4*)&kbuf[ki*196];
        const float4* qp = (const float4*)&qpbuf[qi*148];
        const float4* kp = (const float4*)&kpbuf[ki*148];
        #pragma unroll
        for (int h = 0; h < 12; ++h) {
            float d = 0.f;
            #pragma unroll
            for (int j = 0; j < 4; ++j) {
                float4 a = qv[h*4+j], b = kv[h*4+j];
                d += a.x*b.x + a.y*b.y + a.z*b.z + a.w*b.w;
            }
            float d2 = 0.f;
            #pragma unroll
            for (int j = 0; j < 3; ++j) {
                float4 a = qp[h*3+j], b = kp[h*3+j];
                float t0=a.x-b.x, t1=a.y-b.y, t2=a.z-b.z, t3=a.w-b.w;
                d2 += t0*t0+t1*t1+t2*t2+t3*t3;
            }
            float x = head_w[h];
            float sp = (x > 20.f) ? x : log1pf(__expf(x));
            float coef = -0.5f * sp * 0.13608276348795434f;   // sqrt(1/54)
            lgp[h] = d*scale_qk + coef*d2 + scale_b*b_b[h] + mterm;
        }
    }
    __syncthreads();   // phase boundary: smem reused for z tile

    float* zt = smem;  // stride 37 (conflict-free scalar reads)
    float bp[12];
    #pragma unroll
    for (int h = 0; h < 12; ++h) bp[h] = 0.f;

    for (int cc = 0; cc < 4; ++cc) {
        __syncthreads();
        #pragma unroll
        for (int j = 0; j < 8; ++j) {
            int f = tid + 256*j;            // 0..2047 float4s
            int r = f >> 3, c4 = (f & 7)*4; // r = q,k pair 0..255
            int qq = r >> 4, kk = r & 15;
            float4 v = *(const float4*)(z + ((size_t)(q0+qq)*NRES + (k0+kk))*CZ + cc*32 + c4);
            float* d = &zt[r*37 + c4];
            d[0]=v.x; d[1]=v.y; d[2]=v.z; d[3]=v.w;
        }
        __syncthreads();
        const float* zrow = &zt[tid*37];
        #pragma unroll
        for (int c = 0; c < 32; ++c) {
            float zv = zrow[c];
            const float* wb = &W_b[(cc*32+c)*NH];   // wave-uniform -> scalar loads
            #pragma unroll
            for (int h = 0; h < 12; ++h) bp[h] += zv * wb[h];
        }
    }
    size_t outbase = (size_t)(q0+qi)*NRES + (k0+ki);
    #pragma unroll
    for (int h = 0; h < 12; ++h)
        lg[(size_t)h*NN + outbase] = lgp[h] + scale_b*bp[h];
}

// softmax (in-place on lg) + o + o_pt(tilde) ; wave per (h,q) row
__global__ __launch_bounds__(256) void softmax_opt_kernel(
    float* __restrict__ lg, const float* __restrict__ vcatT,
    float* __restrict__ cat, float* __restrict__ optt)
{
    int row = blockIdx.x*4 + (threadIdx.x >> 6);
    int ln = threadIdx.x & 63;
    int h = row / NRES, q = row % NRES;
    float* arow = lg + (size_t)h*NN + (size_t)q*NRES;
    float4 a[3];
    #pragma unroll
    for (int i=0;i<3;++i) a[i] = *(const float4*)(arow + ln*4 + i*256);
    float m = -1e30f;
    #pragma unroll
    for (int i=0;i<3;++i) m = fmaxf(m, fmaxf(fmaxf(a[i].x,a[i].y),fmaxf(a[i].z,a[i].w)));
    #pragma unroll
    for (int o=32;o>0;o>>=1) m = fmaxf(m, __shfl_xor(m,o,64));
    float s = 0.f;
    #pragma unroll
    for (int i=0;i<3;++i) {
        a[i].x = __expf(a[i].x-m); a[i].y = __expf(a[i].y-m);
        a[i].z = __expf(a[i].z-m); a[i].w = __expf(a[i].w-m);
        s += a[i].x + a[i].y + a[i].z + a[i].w;
    }
    #pragma unroll
    for (int o=32;o>0;o>>=1) s += __shfl_xor(s,o,64);
    float inv = 1.f/s;
    #pragma unroll
    for (int i=0;i<3;++i) {
        a[i].x*=inv; a[i].y*=inv; a[i].z*=inv; a[i].w*=inv;
        *(float4*)(arow + ln*4 + i*256) = a[i];
    }
    for (int col = 0; col < 40; ++col) {
        const float* vrow = vcatT + (size_t)(h*40+col)*NRES;
        float p = 0.f;
        #pragma unroll
        for (int i=0;i<3;++i) {
            float4 v = *(const float4*)(vrow + ln*4 + i*256);
            p += a[i].x*v.x + a[i].y*v.y + a[i].z*v.z + a[i].w*v.w;
        }
        #pragma unroll
        for (int o=32;o>0;o>>=1) p += __shfl_xor(p,o,64);
        if (ln == 0) {
            if (col < 16) cat[(size_t)q*CATC + h*16 + col] = p;
            else          optt[(size_t)q*288 + h*24 + (col-16)] = p;
        }
    }
}

// o_pair: block per q; 16-row z chunks, k-split accumulators
__global__ __launch_bounds__(256) void opair_kernel(
    const float* __restrict__ z, const float* __restrict__ lg,
    const float* __restrict__ rot, const float* __restrict__ trans,
    const float* __restrict__ optt, float* __restrict__ cat)
{
    __shared__ float smem[12288];      // abuf[9216] | zbuf[16*132]; reduction reuses all
    float* abuf = smem;
    float* zbuf = smem + 9216;
    const int q = blockIdx.x, tid = threadIdx.x;
    float* crow = cat + (size_t)q*CATC;

    for (int f = tid; f < 2304; f += 256) {
        int h = f / 192, kk4 = f % 192;
        ((float4*)abuf)[h*192 + kk4] =
            *(const float4*)(lg + (size_t)h*NN + (size_t)q*NRES + kk4*4);
    }
    if (tid < 96) {
        int h = tid>>3, p = tid&7;
        float b0 = optt[(size_t)q*288 + h*24+p*3+0] - trans[q*3+0];
        float b1 = optt[(size_t)q*288 + h*24+p*3+1] - trans[q*3+1];
        float b2 = optt[(size_t)q*288 + h*24+p*3+2] - trans[q*3+2];
        const float* Rm = rot + (size_t)q*9;
        float v0 = Rm[0]*b0 + Rm[3]*b1 + Rm[6]*b2;
        float v1 = Rm[1]*b0 + Rm[4]*b1 + Rm[7]*b2;
        float v2 = Rm[2]*b0 + Rm[5]*b1 + Rm[8]*b2;
        crow[192 + tid] = v0;
        crow[288 + tid] = v1;
        crow[384 + tid] = v2;
        crow[480 + tid] = sqrtf(v0*v0 + v1*v1 + v2*v2 + 1e-8f);
    }

    const int ks = tid>>5, c4 = tid&31;   // 8 k-slices (2 rows each), 32 col groups
    float4 acc[12];
    #pragma unroll
    for (int h=0;h<12;++h) { acc[h].x=0; acc[h].y=0; acc[h].z=0; acc[h].w=0; }

    for (int kc = 0; kc < NRES; kc += 16) {
        __syncthreads();
        #pragma unroll
        for (int j = 0; j < 2; ++j) {
            int f = tid + 256*j;           // 0..511
            int r = f>>5, cc = f&31;
            *(float4*)&zbuf[r*132 + cc*4] =
                *(const float4*)(z + ((size_t)q*NRES + kc + r)*CZ + cc*4);
        }
        __syncthreads();
        float2 av[12];
        #pragma unroll
        for (int h=0;h<12;++h)
            av[h] = *(const float2*)(abuf + h*768 + kc + ks*2);
        #pragma unroll
        for (int i=0;i<2;++i) {
            float4 zv = *(const float4*)(&zbuf[(ks*2+i)*132 + c4*4]);
            #pragma unroll
            for (int h=0;h<12;++h) {
                float aw = i ? av[h].y : av[h].x;
                acc[h].x += aw*zv.x; acc[h].y += aw*zv.y;
                acc[h].z += aw*zv.z; acc[h].w += aw*zv.w;
            }
        }
    }
    __syncthreads();
    #pragma unroll
    for (int h=0;h<12;++h) *((float4*)&smem[tid*48 + h*4]) = acc[h];
    __syncthreads();
    for (int o = tid; o < 384; o += 256) {
        int h = o >> 5, cc = o & 31;
        float4 r = {0,0,0,0};
        #pragma unroll
        for (int k2=0;k2<8;++k2) {
            float4 p = *(const float4*)&smem[(k2*32+cc)*48 + h*4];
            r.x+=p.x; r.y+=p.y; r.z+=p.z; r.w+=p.w;
        }
        *(float4*)(crow + 576 + h*128 + cc*4) = r;
    }
}

// outgemm: 64x64 tile, 4x4 micro, split-K=6, atomicAdd onto bias-init out
__global__ __launch_bounds__(256) void outgemm_kernel(
    const float* __restrict__ cat, const float* __restrict__ W_out,
    float* __restrict__ out)
{
    __shared__ float Al[32][68];   // [k][m]
    __shared__ float Bl[32][68];   // [k][n]
    const int mt = blockIdx.x;     // 0..11
    const int nt = blockIdx.y;     // 0..5
    const int kt = blockIdx.z;     // 0..5 (352 K each)
    const int tid = threadIdx.x;
    const int m0 = (tid & 15)*4, n0 = (tid >> 4)*4;
    float acc[4][4] = {};
    for (int ki = 0; ki < 11; ++ki) {
        int kc = kt*352 + ki*32;
        #pragma unroll
        for (int f = tid; f < 512; f += 256) {
            int r = f >> 3, c4 = (f & 7)*4;
            float4 v = *(const float4*)(cat + (size_t)(mt*64+r)*CATC + kc + c4);
            Al[c4][r]=v.x; Al[c4+1][r]=v.y; Al[c4+2][r]=v.z; Al[c4+3][r]=v.w;
        }
        #pragma unroll
        for (int f = tid; f < 512; f += 256) {
            int r = f >> 4, c4 = (f & 15)*4;
            *(float4*)&Bl[r][c4] = *(const float4*)(W_out + (size_t)(kc+r)*CS + nt*64 + c4);
        }
        __syncthreads();
        #pragma unroll
        for (int kk = 0; kk < 32; ++kk) {
            float4 a = *(const float4*)&Al[kk][m0];
            float4 b = *(const float4*)&Bl[kk][n0];
            acc[0][0]+=a.x*b.x; acc[0][1]+=a.x*b.y; acc[0][2]+=a.x*b.z; acc[0][3]+=a.x*b.w;
            acc[1][0]+=a.y*b.x; acc[1][1]+=a.y*b.y; acc[1][2]+=a.y*b.z; acc[1][3]+=a.y*b.w;
            acc[2][0]+=a.z*b.x; acc[2][1]+=a.z*b.y; acc[2][2]+=a.z*b.z; acc[2][3]+=a.z*b.w;
            acc[3][0]+=a.w*b.x; acc[3][1]+=a.w*b.y; acc[3][2]+=a.w*b.z; acc[3][3]+=a.w*b.w;
        }
        __syncthreads();
    }
    #pragma unroll
    for (int r = 0; r < 4; ++r)
        #pragma unroll
        for (int c = 0; c < 4; ++c)
            atomicAdd(&out[(size_t)(mt*64+m0+r)*CS + nt*64+n0+c], acc[r][c]);
}

extern "C" void kernel_launch(void* const* d_in, const int* in_sizes, int n_in,
                              void* d_out, int out_size, void* d_ws, size_t ws_size,
                              hipStream_t stream) {
    const float* s      = (const float*)d_in[0];
    const float* z      = (const float*)d_in[1];
    const float* rot    = (const float*)d_in[2];
    const float* trans  = (const float*)d_in[3];
    const float* mask   = (const float*)d_in[4];
    const float* W_q    = (const float*)d_in[5];
    const float* b_q    = (const float*)d_in[6];
    const float* W_kv   = (const float*)d_in[7];
    const float* b_kv   = (const float*)d_in[8];
    const float* W_qp   = (const float*)d_in[9];
    const float* b_qp   = (const float*)d_in[10];
    const float* W_kvp  = (const float*)d_in[11];
    const float* b_kvp  = (const float*)d_in[12];
    const float* W_b    = (const float*)d_in[13];
    const float* b_b    = (const float*)d_in[14];
    const float* head_w = (const float*)d_in[15];
    const float* W_out  = (const float*)d_in[16];
    const float* b_out  = (const float*)d_in[17];

    float* ws = (float*)d_ws;
    float* proj_q   = ws;                 // 147456
    float* proj_kv  = ws + 147456;        // 294912
    float* proj_qp  = ws + 442368;        // 110592
    float* proj_kvp = ws + 552960;        // 331776
    float* q_pts    = ws + 884736;        // 110592
    float* k_pts    = ws + 995328;        // 110592
    float* vcatT    = ws + 1105920;       // 368640
    float* optt     = ws + 1474560;       // 221184
    float* cat      = ws + 1695744;       // 1622016
    float* lg       = ws + 3317760;       // 7077888
    float* out = (float*)d_out;

    proj_kernel<<<dim3(12,24), 256, 0, stream>>>(s, W_q, b_q, W_kv, b_kv, W_qp, b_qp, W_kvp, b_kvp,
                                                 proj_q, proj_kv, proj_qp, proj_kvp);
    rotpts_kernel<<<2304, 256, 0, stream>>>(rot, trans, proj_kv, proj_qp, proj_kvp, b_out,
                                            q_pts, k_pts, vcatT, out);
    logits_kernel<<<dim3(48,48), 256, 0, stream>>>(z, mask, head_w, W_b, b_b,
                                                   proj_q, proj_kv, q_pts, k_pts, lg);
    softmax_opt_kernel<<<NRES*NH/4, 256, 0, stream>>>(lg, vcatT, cat, optt);
    opair_kernel<<<NRES, 256, 0, stream>>>(z, lg, rot, trans, optt, cat);
    outgemm_kernel<<<dim3(12,6,6), 256, 0, stream>>>(cat, W_out, out);
}

// Round 4
// 800.933 us; speedup vs baseline: 1.6529x; 1.1797x over previous
//
#include <hip/hip_runtime.h>
#include <hip/hip_bf16.h>
#include <math.h>

#define NRES 768
#define CS   384
#define CZ   128
#define CH   16
#define NH   12
#define PQK  4
#define PV   8
#define QCOLS   (NH*CH)        // 192
#define KVCOLS  (2*NH*CH)      // 384
#define QPCOLS  (NH*PQK*3)     // 144
#define KVPCOLS (NH*(PQK+PV)*3)// 432
#define CATC    (NH*(CZ+CH+PV*4)) // 2112
#define NN      (NRES*NRES)    // 589824

// ---------------- proj: tiled GEMM s(768x384) @ {Wq|Wkv|Wqp|Wkvp} ----------------
__global__ __launch_bounds__(256) void proj_kernel(
    const float* __restrict__ s,
    const float* __restrict__ Wq,  const float* __restrict__ bq,
    const float* __restrict__ Wkv, const float* __restrict__ bkv,
    const float* __restrict__ Wqp, const float* __restrict__ bqp,
    const float* __restrict__ Wkvp,const float* __restrict__ bkvp,
    float* __restrict__ proj_q, float* __restrict__ proj_kv,
    float* __restrict__ proj_qp, float* __restrict__ proj_kvp)
{
    __shared__ float Al[32][68];   // [k][m]
    __shared__ float Bl[32][52];   // [k][n]
    const int mt = blockIdx.x;     // 0..11
    const int gc0 = blockIdx.y * 48;
    const float* W; const float* bb; int ncol; float* dst; int c0;
    if (gc0 < 192)      { W=Wq;   bb=bq;   ncol=QCOLS;   dst=proj_q;   c0=gc0; }
    else if (gc0 < 576) { W=Wkv;  bb=bkv;  ncol=KVCOLS;  dst=proj_kv;  c0=gc0-192; }
    else if (gc0 < 720) { W=Wqp;  bb=bqp;  ncol=QPCOLS;  dst=proj_qp;  c0=gc0-576; }
    else                { W=Wkvp; bb=bkvp; ncol=KVPCOLS; dst=proj_kvp; c0=gc0-720; }
    const int tid = threadIdx.x;
    const int m0 = (tid & 15)*4;
    const int n0 = (tid >> 4)*3;
    float acc[4][3] = {};
    for (int kc = 0; kc < CS; kc += 32) {
        #pragma unroll
        for (int f = tid; f < 512; f += 256) {
            int r = f >> 3, c4 = (f & 7)*4;
            float4 v = *(const float4*)(s + (size_t)(mt*64+r)*CS + kc + c4);
            Al[c4][r]=v.x; Al[c4+1][r]=v.y; Al[c4+2][r]=v.z; Al[c4+3][r]=v.w;
        }
        for (int f = tid; f < 384; f += 256) {
            int r = f / 12, c4 = (f % 12)*4;
            *(float4*)&Bl[r][c4] = *(const float4*)(W + (size_t)(kc+r)*ncol + c0 + c4);
        }
        __syncthreads();
        #pragma unroll
        for (int kk = 0; kk < 32; ++kk) {
            float4 a = *(const float4*)&Al[kk][m0];
            float b0 = Bl[kk][n0], b1 = Bl[kk][n0+1], b2 = Bl[kk][n0+2];
            acc[0][0]+=a.x*b0; acc[0][1]+=a.x*b1; acc[0][2]+=a.x*b2;
            acc[1][0]+=a.y*b0; acc[1][1]+=a.y*b1; acc[1][2]+=a.y*b2;
            acc[2][0]+=a.z*b0; acc[2][1]+=a.z*b1; acc[2][2]+=a.z*b2;
            acc[3][0]+=a.w*b0; acc[3][1]+=a.w*b1; acc[3][2]+=a.w*b2;
        }
        __syncthreads();
    }
    #pragma unroll
    for (int r = 0; r < 4; ++r)
        #pragma unroll
        for (int c = 0; c < 3; ++c)
            dst[(size_t)(mt*64+m0+r)*ncol + c0+n0+c] = acc[r][c] + bb[c0+n0+c];
}

// ---------------- rotpts: points + packed layouts + out bias-init ----------------
// qfrag[q][h][28] = [16 q-chan | 12 q-pt comps]; kcat[h][28][768]; vcatT[h][40][768]
__global__ __launch_bounds__(256) void rotpts_kernel(
    const float* __restrict__ rot, const float* __restrict__ trans,
    const float* __restrict__ proj_q, const float* __restrict__ proj_kv,
    const float* __restrict__ proj_qp, const float* __restrict__ proj_kvp,
    const float* __restrict__ b_out,
    float* __restrict__ qfrag, float* __restrict__ kcat, float* __restrict__ vcatT,
    float* __restrict__ out)
{
    int g = blockIdx.x*256 + threadIdx.x;
    const int S0 = NRES*48;            // 36864  q points (n, h*4+p) -> 3 comps
    const int S1 = S0 + NRES*432;      // kv point comps, n fastest
    const int S2 = S1 + NRES*192;      // proj_q copy -> qfrag
    const int S3 = S2 + NRES*384;      // proj_kv copy -> kcat/vcatT, n fastest
    const int S4 = S3 + NRES*CS;       // out bias init
    if (g < S0) {
        int n = g/48, rem = g%48;
        int h = rem>>2, p = rem&3;
        float p0 = proj_qp[(size_t)n*QPCOLS + rem];
        float p1 = proj_qp[(size_t)n*QPCOLS + 48 + rem];
        float p2 = proj_qp[(size_t)n*QPCOLS + 96 + rem];
        const float* Rm = rot + (size_t)n*9; const float* t = trans + (size_t)n*3;
        float* dq = qfrag + ((size_t)n*12 + h)*28 + 16 + p*3;
        #pragma unroll
        for (int i = 0; i < 3; ++i)
            dq[i] = Rm[i*3]*p0 + Rm[i*3+1]*p1 + Rm[i*3+2]*p2 + t[i];
    } else if (g < S1) {
        int g2 = g - S0;
        int n = g2 % 768, t = g2 / 768;   // t in [0,432)
        int h = t/36, u = t%36, p = u/3, i = u%3;
        int col = h*12 + p;
        float p0 = proj_kvp[(size_t)n*KVPCOLS + col];
        float p1 = proj_kvp[(size_t)n*KVPCOLS + 144 + col];
        float p2 = proj_kvp[(size_t)n*KVPCOLS + 288 + col];
        float val = rot[(size_t)n*9 + i*3]*p0 + rot[(size_t)n*9 + i*3+1]*p1
                  + rot[(size_t)n*9 + i*3+2]*p2 + trans[(size_t)n*3 + i];
        if (p < PQK) kcat[(size_t)(h*28 + 16 + p*3 + i)*NRES + n] = val;
        else         vcatT[(size_t)(h*40 + 16 + (p-4)*3 + i)*NRES + n] = val;
    } else if (g < S2) {
        int g3 = g - S1;
        int n = g3 / 192, c = g3 % 192;
        int h = c >> 4, cc = c & 15;
        qfrag[((size_t)n*12 + h)*28 + cc] = proj_q[(size_t)n*QCOLS + c];
    } else if (g < S3) {
        int g4 = g - S2;
        int n = g4 % 768, col = g4 / 768;   // col in [0,384)
        int h = col >> 5, cc = col & 31;
        float val = proj_kv[(size_t)n*KVCOLS + col];
        if (cc < 16) kcat[(size_t)(h*28 + cc)*NRES + n] = val;
        else         vcatT[(size_t)(h*40 + (cc-16))*NRES + n] = val;
    } else if (g < S4) {
        int g5 = g - S3;
        out[g5] = b_out[g5 % CS];
    }
}

// ---------------- bias: lg[h][q*768+k] = scale_b*(z@W_b + b_b) + mask term ----------------
__global__ __launch_bounds__(256) void bias_kernel(
    const float* __restrict__ z, const float* __restrict__ mask,
    const float* __restrict__ W_b, const float* __restrict__ b_b,
    float* __restrict__ lg)
{
    int r = blockIdx.x*256 + threadIdx.x;     // 0..589823
    int q = r / 768, k = r - q*768;
    const float4* zr = (const float4*)(z + (size_t)r*CZ);
    float acc[12] = {};
    #pragma unroll
    for (int c4 = 0; c4 < 32; ++c4) {
        float4 v = zr[c4];
        const float* w0 = W_b + c4*48;        // wave-uniform -> scalar loads
        #pragma unroll
        for (int h = 0; h < 12; ++h)
            acc[h] += v.x*w0[h] + v.y*w0[12+h] + v.z*w0[24+h] + v.w*w0[36+h];
    }
    float mterm = 100000.0f*(mask[q]*mask[k] - 1.0f);
    const float scale_b = 0.5773502691896258f;   // sqrt(1/3)
    #pragma unroll
    for (int h = 0; h < 12; ++h)
        lg[(size_t)h*NN + r] = scale_b*(acc[h] + b_b[h]) + mterm;
}

// ---------------- softmax_fused: qk+pt logits + softmax + o + o_pt ----------------
// block = (h, 4 consecutive q), wave per q. kcat/vcatT[h] shared via L1.
__global__ __launch_bounds__(256) void softmax_fused_kernel(
    float* __restrict__ lg, const float* __restrict__ qfrag, const float* __restrict__ kcat,
    const float* __restrict__ head_w, const float* __restrict__ vcatT,
    float* __restrict__ cat, float* __restrict__ optt)
{
    const int h = blockIdx.x % 12;
    const int q = (blockIdx.x / 12)*4 + (threadIdx.x >> 6);
    const int ln = threadIdx.x & 63;
    const float scale_qk = 0.14433756729740643f;  // sqrt(1/48)
    float x = head_w[h];
    float sp = (x > 20.f) ? x : log1pf(__expf(x));
    float coef = -0.5f * sp * 0.13608276348795434f;   // sqrt(1/54)

    float qf[28];
    const float* qp = qfrag + ((size_t)q*12 + h)*28;
    #pragma unroll
    for (int c = 0; c < 28; ++c) qf[c] = qp[c];

    float* arow = lg + (size_t)h*NN + (size_t)q*NRES;
    const float* kb = kcat + (size_t)h*28*NRES;
    float4 a[3];
    #pragma unroll
    for (int i = 0; i < 3; ++i) {
        a[i] = *(const float4*)(arow + ln*4 + i*256);
        float4 d = {0.f,0.f,0.f,0.f}, p2 = {0.f,0.f,0.f,0.f};
        #pragma unroll
        for (int c = 0; c < 16; ++c) {
            float4 kv = *(const float4*)(kb + (size_t)c*NRES + ln*4 + i*256);
            d.x += qf[c]*kv.x; d.y += qf[c]*kv.y; d.z += qf[c]*kv.z; d.w += qf[c]*kv.w;
        }
        #pragma unroll
        for (int c = 16; c < 28; ++c) {
            float4 kv = *(const float4*)(kb + (size_t)c*NRES + ln*4 + i*256);
            float t0 = qf[c]-kv.x, t1 = qf[c]-kv.y, t2 = qf[c]-kv.z, t3 = qf[c]-kv.w;
            p2.x += t0*t0; p2.y += t1*t1; p2.z += t2*t2; p2.w += t3*t3;
        }
        a[i].x += scale_qk*d.x + coef*p2.x;
        a[i].y += scale_qk*d.y + coef*p2.y;
        a[i].z += scale_qk*d.z + coef*p2.z;
        a[i].w += scale_qk*d.w + coef*p2.w;
    }
    // softmax over 768
    float m = -1e30f;
    #pragma unroll
    for (int i=0;i<3;++i) m = fmaxf(m, fmaxf(fmaxf(a[i].x,a[i].y),fmaxf(a[i].z,a[i].w)));
    #pragma unroll
    for (int o=32;o>0;o>>=1) m = fmaxf(m, __shfl_xor(m,o,64));
    float ssum = 0.f;
    #pragma unroll
    for (int i=0;i<3;++i) {
        a[i].x = __expf(a[i].x-m); a[i].y = __expf(a[i].y-m);
        a[i].z = __expf(a[i].z-m); a[i].w = __expf(a[i].w-m);
        ssum += a[i].x + a[i].y + a[i].z + a[i].w;
    }
    #pragma unroll
    for (int o=32;o>0;o>>=1) ssum += __shfl_xor(ssum,o,64);
    float inv = 1.f/ssum;
    #pragma unroll
    for (int i=0;i<3;++i) {
        a[i].x*=inv; a[i].y*=inv; a[i].z*=inv; a[i].w*=inv;
        *(float4*)(arow + ln*4 + i*256) = a[i];
    }
    // o (16 cols) + o_pt tilde (24 cols)
    for (int col = 0; col < 40; ++col) {
        const float* vrow = vcatT + (size_t)(h*40+col)*NRES;
        float p = 0.f;
        #pragma unroll
        for (int i=0;i<3;++i) {
            float4 v = *(const float4*)(vrow + ln*4 + i*256);
            p += a[i].x*v.x + a[i].y*v.y + a[i].z*v.z + a[i].w*v.w;
        }
        #pragma unroll
        for (int o=32;o>0;o>>=1) p += __shfl_xor(p,o,64);
        if (ln == 0) {
            if (col < 16) cat[(size_t)q*CATC + h*16 + col] = p;
            else          optt[(size_t)q*288 + h*24 + (col-16)] = p;
        }
    }
}

// ---------------- o_pair: block per q, thread=(h,c8), direct z stream ----------------
__global__ __launch_bounds__(192) void opair_kernel(
    const float* __restrict__ z, const float* __restrict__ lg,
    const float* __restrict__ rot, const float* __restrict__ trans,
    const float* __restrict__ optt, float* __restrict__ cat)
{
    __shared__ float4 abuf4[2304];     // a[12][768]
    float* abuf = (float*)abuf4;
    const int q = blockIdx.x, tid = threadIdx.x;
    float* crow = cat + (size_t)q*CATC;

    for (int f = tid; f < 2304; f += 192) {
        int hh = f / 192, k4 = f % 192;
        abuf4[hh*192 + k4] = *(const float4*)(lg + (size_t)hh*NN + (size_t)q*NRES + k4*4);
    }
    __syncthreads();
    if (tid < 96) {
        int hh = tid>>3, p = tid&7;
        float b0 = optt[(size_t)q*288 + hh*24+p*3+0] - trans[q*3+0];
        float b1 = optt[(size_t)q*288 + hh*24+p*3+1] - trans[q*3+1];
        float b2 = optt[(size_t)q*288 + hh*24+p*3+2] - trans[q*3+2];
        const float* Rm = rot + (size_t)q*9;
        float v0 = Rm[0]*b0 + Rm[3]*b1 + Rm[6]*b2;
        float v1 = Rm[1]*b0 + Rm[4]*b1 + Rm[7]*b2;
        float v2 = Rm[2]*b0 + Rm[5]*b1 + Rm[8]*b2;
        crow[192 + tid] = v0;
        crow[288 + tid] = v1;
        crow[384 + tid] = v2;
        crow[480 + tid] = sqrtf(v0*v0 + v1*v1 + v2*v2 + 1e-8f);
    }
    const int h = tid >> 4, c8 = (tid & 15)*8;
    const float* zq = z + (size_t)q*NRES*CZ + c8;
    const float* ah = abuf + h*768;
    float4 acc0 = {0.f,0.f,0.f,0.f}, acc1 = {0.f,0.f,0.f,0.f};
    #pragma unroll 4
    for (int k = 0; k < NRES; ++k) {
        float aw = ah[k];
        float4 z0 = *(const float4*)(zq + (size_t)k*CZ);
        float4 z1 = *(const float4*)(zq + (size_t)k*CZ + 4);
        acc0.x += aw*z0.x; acc0.y += aw*z0.y; acc0.z += aw*z0.z; acc0.w += aw*z0.w;
        acc1.x += aw*z1.x; acc1.y += aw*z1.y; acc1.z += aw*z1.z; acc1.w += aw*z1.w;
    }
    *(float4*)(crow + 576 + h*128 + c8)     = acc0;
    *(float4*)(crow + 576 + h*128 + c8 + 4) = acc1;
}

// ---------------- outgemm: 64x64 tile, 4x4 micro, split-K=6, atomicAdd ----------------
__global__ __launch_bounds__(256) void outgemm_kernel(
    const float* __restrict__ cat, const float* __restrict__ W_out,
    float* __restrict__ out)
{
    __shared__ float Al[32][68];   // [k][m]
    __shared__ float Bl[32][68];   // [k][n]
    const int mt = blockIdx.x;     // 0..11
    const int nt = blockIdx.y;     // 0..5
    const int kt = blockIdx.z;     // 0..5 (352 K each)
    const int tid = threadIdx.x;
    const int m0 = (tid & 15)*4, n0 = (tid >> 4)*4;
    float acc[4][4] = {};
    for (int ki = 0; ki < 11; ++ki) {
        int kc = kt*352 + ki*32;
        #pragma unroll
        for (int f = tid; f < 512; f += 256) {
            int r = f >> 3, c4 = (f & 7)*4;
            float4 v = *(const float4*)(cat + (size_t)(mt*64+r)*CATC + kc + c4);
            Al[c4][r]=v.x; Al[c4+1][r]=v.y; Al[c4+2][r]=v.z; Al[c4+3][r]=v.w;
        }
        #pragma unroll
        for (int f = tid; f < 512; f += 256) {
            int r = f >> 4, c4 = (f & 15)*4;
            *(float4*)&Bl[r][c4] = *(const float4*)(W_out + (size_t)(kc+r)*CS + nt*64 + c4);
        }
        __syncthreads();
        #pragma unroll
        for (int kk = 0; kk < 32; ++kk) {
            float4 a = *(const float4*)&Al[kk][m0];
            float4 b = *(const float4*)&Bl[kk][n0];
            acc[0][0]+=a.x*b.x; acc[0][1]+=a.x*b.y; acc[0][2]+=a.x*b.z; acc[0][3]+=a.x*b.w;
            acc[1][0]+=a.y*b.x; acc[1][1]+=a.y*b.y; acc[1][2]+=a.y*b.z; acc[1][3]+=a.y*b.w;
            acc[2][0]+=a.z*b.x; acc[2][1]+=a.z*b.y; acc[2][2]+=a.z*b.z; acc[2][3]+=a.z*b.w;
            acc[3][0]+=a.w*b.x; acc[3][1]+=a.w*b.y; acc[3][2]+=a.w*b.z; acc[3][3]+=a.w*b.w;
        }
        __syncthreads();
    }
    #pragma unroll
    for (int r = 0; r < 4; ++r)
        #pragma unroll
        for (int c = 0; c < 4; ++c)
            atomicAdd(&out[(size_t)(mt*64+m0+r)*CS + nt*64+n0+c], acc[r][c]);
}

extern "C" void kernel_launch(void* const* d_in, const int* in_sizes, int n_in,
                              void* d_out, int out_size, void* d_ws, size_t ws_size,
                              hipStream_t stream) {
    const float* s      = (const float*)d_in[0];
    const float* z      = (const float*)d_in[1];
    const float* rot    = (const float*)d_in[2];
    const float* trans  = (const float*)d_in[3];
    const float* mask   = (const float*)d_in[4];
    const float* W_q    = (const float*)d_in[5];
    const float* b_q    = (const float*)d_in[6];
    const float* W_kv   = (const float*)d_in[7];
    const float* b_kv   = (const float*)d_in[8];
    const float* W_qp   = (const float*)d_in[9];
    const float* b_qp   = (const float*)d_in[10];
    const float* W_kvp  = (const float*)d_in[11];
    const float* b_kvp  = (const float*)d_in[12];
    const float* W_b    = (const float*)d_in[13];
    const float* b_b    = (const float*)d_in[14];
    const float* head_w = (const float*)d_in[15];
    const float* W_out  = (const float*)d_in[16];
    const float* b_out  = (const float*)d_in[17];

    float* ws = (float*)d_ws;
    // lg occupies [0, 7077888); proj_* alias its head (dead before bias_kernel writes lg)
    float* lg       = ws;
    float* proj_q   = ws;                 // 147456
    float* proj_kv  = ws + 147456;        // 294912
    float* proj_qp  = ws + 442368;        // 110592
    float* proj_kvp = ws + 552960;        // 331776 (ends 884736 < 7077888)
    float* vcatT    = ws + 7077888;       // 368640
    float* qfrag    = ws + 7446528;       // 258048
    float* kcat     = ws + 7704576;       // 258048
    float* optt     = ws + 7962624;       // 221184
    float* cat      = ws + 8183808;       // 1622016 (total 9805824 floats = 39.2 MB)
    float* out = (float*)d_out;

    proj_kernel<<<dim3(12,24), 256, 0, stream>>>(s, W_q, b_q, W_kv, b_kv, W_qp, b_qp, W_kvp, b_kvp,
                                                 proj_q, proj_kv, proj_qp, proj_kvp);
    rotpts_kernel<<<4320, 256, 0, stream>>>(rot, trans, proj_q, proj_kv, proj_qp, proj_kvp, b_out,
                                            qfrag, kcat, vcatT, out);
    bias_kernel<<<NN/256, 256, 0, stream>>>(z, mask, W_b, b_b, lg);
    softmax_fused_kernel<<<12*(NRES/4), 256, 0, stream>>>(lg, qfrag, kcat, head_w, vcatT, cat, optt);
    opair_kernel<<<NRES, 192, 0, stream>>>(z, lg, rot, trans, optt, cat);
    outgemm_kernel<<<dim3(12,6,6), 256, 0, stream>>>(cat, W_out, out);
}